// Round 5
// baseline (3979.878 us; speedup 1.0000x reference)
//
#include <hip/hip_runtime.h>
#include <math.h>

#define B_   32
#define C_   512
#define CR_  32
#define HW_  4096
#define NCH  16           // channel chunks
#define CPB  (C_/NCH)     // 32 channels per chunk
#define EPSV 1e-5f

typedef float v4f __attribute__((ext_vector_type(4)));

// ---- k1: partial logits. partial[b][ch][s] = sum_{c in chunk} w[c]*x[b,c,s]
__global__ __launch_bounds__(256) void k1_logits_partial(
    const float* __restrict__ x, const float* __restrict__ w_mask,
    float* __restrict__ partial)
{
    const int b = blockIdx.y, ch = blockIdx.x, t = threadIdx.x;
    const int s0 = blockIdx.z * 512;            // float4 offset of this half
    const int c0 = ch * CPB;
    float4 a0 = {0,0,0,0}, a1 = {0,0,0,0};
#pragma unroll 4
    for (int cc = 0; cc < CPB; ++cc) {
        const float w = w_mask[c0 + cc];
        const float4* px = reinterpret_cast<const float4*>(x + (size_t)(b * C_ + c0 + cc) * HW_) + s0;
        float4 v;
        v = px[t      ]; a0.x += w*v.x; a0.y += w*v.y; a0.z += w*v.z; a0.w += w*v.w;
        v = px[t + 256]; a1.x += w*v.x; a1.y += w*v.y; a1.z += w*v.z; a1.w += w*v.w;
    }
    float4* pp = reinterpret_cast<float4*>(partial + (size_t)(b * NCH + ch) * HW_) + s0;
    pp[t      ] = a0;
    pp[t + 256] = a1;
}

// ---- k2: fused partial-reduce + softmax over HW per batch
__global__ __launch_bounds__(256) void k2_softmax(
    const float* __restrict__ partial, float* __restrict__ attn)
{
    __shared__ float l4[4];
    __shared__ float sM, sZ;
    const int b = blockIdx.x, t = threadIdx.x;
    const int lane = t & 63, wid = t >> 6;
    float4 v[4];
#pragma unroll
    for (int k = 0; k < 4; ++k) {
        float4 s = {0,0,0,0};
        const int i = t + 256 * k;
#pragma unroll
        for (int ch = 0; ch < NCH; ++ch) {
            const float4 p = reinterpret_cast<const float4*>(partial + (size_t)(b * NCH + ch) * HW_)[i];
            s.x += p.x; s.y += p.y; s.z += p.z; s.w += p.w;
        }
        v[k] = s;
    }
    float mx = -3.0e38f;
#pragma unroll
    for (int k = 0; k < 4; ++k)
        mx = fmaxf(mx, fmaxf(fmaxf(v[k].x, v[k].y), fmaxf(v[k].z, v[k].w)));
#pragma unroll
    for (int o = 32; o > 0; o >>= 1) mx = fmaxf(mx, __shfl_down(mx, o));
    if (lane == 0) l4[wid] = mx;
    __syncthreads();
    if (t == 0) sM = fmaxf(fmaxf(l4[0], l4[1]), fmaxf(l4[2], l4[3]));
    __syncthreads();
    const float M = sM;
    float e[16];
    float sum = 0.f;
#pragma unroll
    for (int k = 0; k < 4; ++k) {
        e[k*4+0] = expf(v[k].x - M);
        e[k*4+1] = expf(v[k].y - M);
        e[k*4+2] = expf(v[k].z - M);
        e[k*4+3] = expf(v[k].w - M);
        sum += e[k*4+0] + e[k*4+1] + e[k*4+2] + e[k*4+3];
    }
#pragma unroll
    for (int o = 32; o > 0; o >>= 1) sum += __shfl_down(sum, o);
    __syncthreads();
    if (lane == 0) l4[wid] = sum;
    __syncthreads();
    if (t == 0) sZ = l4[0] + l4[1] + l4[2] + l4[3];
    __syncthreads();
    const float rz = 1.f / sZ;
    float4* pa = reinterpret_cast<float4*>(attn + (size_t)b * HW_);
#pragma unroll
    for (int k = 0; k < 4; ++k)
        pa[t + 256 * k] = make_float4(e[k*4+0]*rz, e[k*4+1]*rz, e[k*4+2]*rz, e[k*4+3]*rz);
}

// ---- kB: fused context+stats -> (last block per batch: MLP gate) -> apply.
// x row stays in registers across the per-batch sync; eliminates the 3rd x read.
__global__ __launch_bounds__(256) void kB_ctx_mlp_apply(
    const float* __restrict__ x, const float* __restrict__ attn,
    const float* __restrict__ w1, const float* __restrict__ b1,
    const float* __restrict__ ln_g, const float* __restrict__ ln_b,
    const float* __restrict__ w2, const float* __restrict__ b2,
    float* __restrict__ ctx, float* __restrict__ sums, float* __restrict__ sqs,
    float* __restrict__ Ab, float* __restrict__ Db,
    int* __restrict__ counter, int* __restrict__ flag,
    float* __restrict__ out)
{
    __shared__ float ld[12];
    __shared__ float cs[C_];
    __shared__ float tl[CR_];
    __shared__ float sAD[2];
    __shared__ int   isLastS;

    const int b = blockIdx.y, c = blockIdx.x, t = threadIdx.x;
    const int lane = t & 63, wid = t >> 6;
    const size_t base = (size_t)(b * C_ + c) * HW_;
    const float4* px = reinterpret_cast<const float4*>(x + base);
    const float4* pa = reinterpret_cast<const float4*>(attn + (size_t)b * HW_);

    // ---- phase 1: load x row into registers, context + stats ----
    float4 xv[4];
    float dot = 0.f, sm = 0.f, sq = 0.f;
#pragma unroll
    for (int k = 0; k < 4; ++k) {
        xv[k] = px[t + 256 * k];
        const float4 av = pa[t + 256 * k];
        dot += xv[k].x*av.x + xv[k].y*av.y + xv[k].z*av.z + xv[k].w*av.w;
        sm  += xv[k].x + xv[k].y + xv[k].z + xv[k].w;
        sq  += xv[k].x*xv[k].x + xv[k].y*xv[k].y + xv[k].z*xv[k].z + xv[k].w*xv[k].w;
    }
#pragma unroll
    for (int o = 32; o > 0; o >>= 1) {
        dot += __shfl_down(dot, o);
        sm  += __shfl_down(sm, o);
        sq  += __shfl_down(sq, o);
    }
    if (lane == 0) { ld[wid] = dot; ld[4 + wid] = sm; ld[8 + wid] = sq; }
    __syncthreads();
    if (t == 0) {
        const int idx = b * C_ + c;
        __hip_atomic_store(&ctx [idx], ld[0] + ld[1] + ld[2]  + ld[3],
                           __ATOMIC_RELAXED, __HIP_MEMORY_SCOPE_AGENT);
        __hip_atomic_store(&sums[idx], ld[4] + ld[5] + ld[6]  + ld[7],
                           __ATOMIC_RELAXED, __HIP_MEMORY_SCOPE_AGENT);
        __hip_atomic_store(&sqs [idx], ld[8] + ld[9] + ld[10] + ld[11],
                           __ATOMIC_RELAXED, __HIP_MEMORY_SCOPE_AGENT);
        const int old = __hip_atomic_fetch_add(&counter[b], 1,
                           __ATOMIC_ACQ_REL, __HIP_MEMORY_SCOPE_AGENT);
        isLastS = (old == C_ - 1);
    }
    __syncthreads();

    // ---- phase 2 (last block of batch b only): bottleneck MLP -> Ab/Db ----
    if (isLastS) {
        cs[t]       = __hip_atomic_load(&ctx[b * C_ + t],       __ATOMIC_RELAXED, __HIP_MEMORY_SCOPE_AGENT);
        cs[t + 256] = __hip_atomic_load(&ctx[b * C_ + t + 256], __ATOMIC_RELAXED, __HIP_MEMORY_SCOPE_AGENT);
        __syncthreads();

        const int row = t >> 3, sub = t & 7;
        float p = 0.f;
#pragma unroll 4
        for (int k = 0; k < 64; ++k) {
            const int cc = sub + (k << 3);
            p += cs[cc] * w1[row * C_ + cc];
        }
        p += __shfl_down(p, 4, 8);
        p += __shfl_down(p, 2, 8);
        p += __shfl_down(p, 1, 8);
        if (sub == 0) tl[row] = p + b1[row];
        __syncthreads();

        float tn = 0.f;
        if (t < CR_) {
            float mu = 0.f;
#pragma unroll
            for (int i = 0; i < CR_; ++i) mu += tl[i];
            mu *= (1.f / CR_);
            float var = 0.f;
#pragma unroll
            for (int i = 0; i < CR_; ++i) { const float d = tl[i] - mu; var += d * d; }
            var *= (1.f / CR_);
            tn = (tl[t] - mu) * rsqrtf(var + EPSV) * ln_g[t] + ln_b[t];
            tn = fmaxf(tn, 0.f);
        }
        __syncthreads();
        if (t < CR_) tl[t] = tn;
        __syncthreads();

#pragma unroll
        for (int r = 0; r < 2; ++r) {
            const int cc = t + r * 256;
            float g = b2[cc];
#pragma unroll 8
            for (int i = 0; i < CR_; ++i) g += tl[i] * w2[cc * CR_ + i];
            g = 1.f / (1.f + expf(-g));
            const float s1 = __hip_atomic_load(&sums[b * C_ + cc], __ATOMIC_RELAXED, __HIP_MEMORY_SCOPE_AGENT);
            const float s2 = __hip_atomic_load(&sqs [b * C_ + cc], __ATOMIC_RELAXED, __HIP_MEMORY_SCOPE_AGENT);
            const float m  = s1 * (1.f / HW_);
            const float v  = s2 * (1.f / HW_) - m * m;
            const float rn = rsqrtf(v + EPSV);
            __hip_atomic_store(&Ab[b * C_ + cc], g + (1.f - g) * rn,
                               __ATOMIC_RELAXED, __HIP_MEMORY_SCOPE_AGENT);
            __hip_atomic_store(&Db[b * C_ + cc], -(1.f - g) * rn * m,
                               __ATOMIC_RELAXED, __HIP_MEMORY_SCOPE_AGENT);
        }
        __syncthreads();   // drains all waves' stores (waitcnt before barrier)
        if (t == 0)
            __hip_atomic_store(&flag[b], 1, __ATOMIC_RELEASE, __HIP_MEMORY_SCOPE_AGENT);
    }

    // ---- phase 3: wait for gate, apply from registers ----
    if (t == 0) {
        while (__hip_atomic_load(&flag[b], __ATOMIC_ACQUIRE, __HIP_MEMORY_SCOPE_AGENT) == 0)
            __builtin_amdgcn_s_sleep(8);
        sAD[0] = __hip_atomic_load(&Ab[b * C_ + c], __ATOMIC_RELAXED, __HIP_MEMORY_SCOPE_AGENT);
        sAD[1] = __hip_atomic_load(&Db[b * C_ + c], __ATOMIC_RELAXED, __HIP_MEMORY_SCOPE_AGENT);
    }
    __syncthreads();
    const float a = sAD[0], d = sAD[1];
    v4f* po = reinterpret_cast<v4f*>(out + base);
#pragma unroll
    for (int k = 0; k < 4; ++k) {
        v4f r;
        r.x = fmaf(a, xv[k].x, d); r.y = fmaf(a, xv[k].y, d);
        r.z = fmaf(a, xv[k].z, d); r.w = fmaf(a, xv[k].w, d);
        __builtin_nontemporal_store(r, po + t + 256 * k);
    }
}

extern "C" void kernel_launch(void* const* d_in, const int* in_sizes, int n_in,
                              void* d_out, int out_size, void* d_ws, size_t ws_size,
                              hipStream_t stream)
{
    const float* x      = (const float*)d_in[0];
    const float* w_mask = (const float*)d_in[1];
    // d_in[2] = b_mask: constant shift, cancels in softmax
    const float* w1     = (const float*)d_in[3];
    const float* b1     = (const float*)d_in[4];
    const float* ln_g   = (const float*)d_in[5];
    const float* ln_b   = (const float*)d_in[6];
    const float* w2     = (const float*)d_in[7];
    const float* b2     = (const float*)d_in[8];
    float* out = (float*)d_out;

    float* ws      = (float*)d_ws;
    float* partial = ws;                               // B*NCH*HW = 2M floats (8 MB)
    float* attn    = partial + (size_t)B_ * NCH * HW_; // B*HW
    float* ctx     = attn   + B_ * HW_;                // B*C
    float* sums    = ctx    + B_ * C_;                 // B*C
    float* sqs     = sums   + B_ * C_;                 // B*C
    float* Ab      = sqs    + B_ * C_;                 // B*C
    float* Db      = Ab     + B_ * C_;                 // B*C
    int*   syncbuf = (int*)(Db + B_ * C_);             // counter[32] + flag[32]

    hipMemsetAsync(syncbuf, 0, 2 * B_ * sizeof(int), stream);
    k1_logits_partial<<<dim3(NCH, B_, 2), 256, 0, stream>>>(x, w_mask, partial);
    k2_softmax<<<B_, 256, 0, stream>>>(partial, attn);
    kB_ctx_mlp_apply<<<dim3(C_, B_), 256, 0, stream>>>(
        x, attn, w1, b1, ln_g, ln_b, w2, b2,
        ctx, sums, sqs, Ab, Db, syncbuf, syncbuf + B_, out);
}

// Round 6
// 196.442 us; speedup vs baseline: 20.2598x; 20.2598x over previous
//
#include <hip/hip_runtime.h>
#include <math.h>

#define B_   32
#define C_   512
#define CR_  32
#define HW_  4096
#define NCH  16           // channel chunks
#define CPB  (C_/NCH)     // 32 channels per chunk
#define NBC  16           // batches per pipeline chunk (x-chunk = 128 MB < L3)
#define EPSV 1e-5f

typedef float v4f __attribute__((ext_vector_type(4)));

// ---- k1: partial logits. partial[b][ch][s] = sum_{c in chunk} w[c]*x[b,c,s]
__global__ __launch_bounds__(256) void k1_logits_partial(
    const float* __restrict__ x, const float* __restrict__ w_mask,
    float* __restrict__ partial, int b0)
{
    const int b = blockIdx.y + b0, ch = blockIdx.x, t = threadIdx.x;
    const int s0 = blockIdx.z * 512;            // float4 offset of this half
    const int c0 = ch * CPB;
    float4 a0 = {0,0,0,0}, a1 = {0,0,0,0};
#pragma unroll 4
    for (int cc = 0; cc < CPB; ++cc) {
        const float w = w_mask[c0 + cc];
        const float4* px = reinterpret_cast<const float4*>(x + (size_t)(b * C_ + c0 + cc) * HW_) + s0;
        float4 v;
        v = px[t      ]; a0.x += w*v.x; a0.y += w*v.y; a0.z += w*v.z; a0.w += w*v.w;
        v = px[t + 256]; a1.x += w*v.x; a1.y += w*v.y; a1.z += w*v.z; a1.w += w*v.w;
    }
    float4* pp = reinterpret_cast<float4*>(partial + (size_t)(b * NCH + ch) * HW_) + s0;
    pp[t      ] = a0;
    pp[t + 256] = a1;
}

// ---- k2: fused partial-reduce + softmax over HW per batch
__global__ __launch_bounds__(256) void k2_softmax(
    const float* __restrict__ partial, float* __restrict__ attn, int b0)
{
    __shared__ float l4[4];
    __shared__ float sM, sZ;
    const int b = blockIdx.x + b0, t = threadIdx.x;
    const int lane = t & 63, wid = t >> 6;
    float4 v[4];
#pragma unroll
    for (int k = 0; k < 4; ++k) {
        float4 s = {0,0,0,0};
        const int i = t + 256 * k;
#pragma unroll
        for (int ch = 0; ch < NCH; ++ch) {
            const float4 p = reinterpret_cast<const float4*>(partial + (size_t)(b * NCH + ch) * HW_)[i];
            s.x += p.x; s.y += p.y; s.z += p.z; s.w += p.w;
        }
        v[k] = s;
    }
    float mx = -3.0e38f;
#pragma unroll
    for (int k = 0; k < 4; ++k)
        mx = fmaxf(mx, fmaxf(fmaxf(v[k].x, v[k].y), fmaxf(v[k].z, v[k].w)));
#pragma unroll
    for (int o = 32; o > 0; o >>= 1) mx = fmaxf(mx, __shfl_down(mx, o));
    if (lane == 0) l4[wid] = mx;
    __syncthreads();
    if (t == 0) sM = fmaxf(fmaxf(l4[0], l4[1]), fmaxf(l4[2], l4[3]));
    __syncthreads();
    const float M = sM;
    float e[16];
    float sum = 0.f;
#pragma unroll
    for (int k = 0; k < 4; ++k) {
        e[k*4+0] = expf(v[k].x - M);
        e[k*4+1] = expf(v[k].y - M);
        e[k*4+2] = expf(v[k].z - M);
        e[k*4+3] = expf(v[k].w - M);
        sum += e[k*4+0] + e[k*4+1] + e[k*4+2] + e[k*4+3];
    }
#pragma unroll
    for (int o = 32; o > 0; o >>= 1) sum += __shfl_down(sum, o);
    __syncthreads();
    if (lane == 0) l4[wid] = sum;
    __syncthreads();
    if (t == 0) sZ = l4[0] + l4[1] + l4[2] + l4[3];
    __syncthreads();
    const float rz = 1.f / sZ;
    float4* pa = reinterpret_cast<float4*>(attn + (size_t)b * HW_);
#pragma unroll
    for (int k = 0; k < 4; ++k)
        pa[t + 256 * k] = make_float4(e[k*4+0]*rz, e[k*4+1]*rz, e[k*4+2]*rz, e[k*4+3]*rz);
}

// ---- k3: context + instance-norm stats in one sweep of x[b,c,:]
__global__ __launch_bounds__(256) void k3_context_stats(
    const float* __restrict__ x, const float* __restrict__ attn,
    float* __restrict__ ctx, float* __restrict__ sums, float* __restrict__ sqs, int b0)
{
    __shared__ float ld[12];
    const int b = blockIdx.y + b0, c = blockIdx.x, t = threadIdx.x;
    const int lane = t & 63, wid = t >> 6;
    const float4* px = reinterpret_cast<const float4*>(x + (size_t)(b * C_ + c) * HW_);
    const float4* pa = reinterpret_cast<const float4*>(attn + (size_t)b * HW_);
    float dot = 0.f, sm = 0.f, sq = 0.f;
#pragma unroll
    for (int k = 0; k < 4; ++k) {
        const float4 xv = px[t + 256 * k];
        const float4 av = pa[t + 256 * k];
        dot += xv.x*av.x + xv.y*av.y + xv.z*av.z + xv.w*av.w;
        sm  += xv.x + xv.y + xv.z + xv.w;
        sq  += xv.x*xv.x + xv.y*xv.y + xv.z*xv.z + xv.w*xv.w;
    }
#pragma unroll
    for (int o = 32; o > 0; o >>= 1) {
        dot += __shfl_down(dot, o);
        sm  += __shfl_down(sm, o);
        sq  += __shfl_down(sq, o);
    }
    if (lane == 0) { ld[wid] = dot; ld[4 + wid] = sm; ld[8 + wid] = sq; }
    __syncthreads();
    if (t == 0) {
        ctx [b * C_ + c] = ld[0] + ld[1] + ld[2]  + ld[3];
        sums[b * C_ + c] = ld[4] + ld[5] + ld[6]  + ld[7];
        sqs [b * C_ + c] = ld[8] + ld[9] + ld[10] + ld[11];
    }
}

// ---- k4: MLP gate + fold instance-norm stats into (A,D): out = A*x + D
__global__ __launch_bounds__(256) void k4_mlp(
    const float* __restrict__ ctx, const float* __restrict__ w1, const float* __restrict__ b1,
    const float* __restrict__ ln_g, const float* __restrict__ ln_b,
    const float* __restrict__ w2, const float* __restrict__ b2,
    const float* __restrict__ sums, const float* __restrict__ sqs,
    float* __restrict__ Ab, float* __restrict__ Db, int b0)
{
    __shared__ float cs[C_];
    __shared__ float tl[CR_];
    const int b = blockIdx.x + b0, t = threadIdx.x;
    cs[t]       = ctx[b * C_ + t];
    cs[t + 256] = ctx[b * C_ + t + 256];
    __syncthreads();

    const int row = t >> 3, sub = t & 7;
    float p = 0.f;
#pragma unroll 8
    for (int k = 0; k < 64; ++k) {
        const int c = sub + (k << 3);
        p += cs[c] * w1[row * C_ + c];
    }
    p += __shfl_down(p, 4, 8);
    p += __shfl_down(p, 2, 8);
    p += __shfl_down(p, 1, 8);
    if (sub == 0) tl[row] = p + b1[row];
    __syncthreads();

    float tn = 0.f;
    if (t < CR_) {
        float mu = 0.f;
#pragma unroll
        for (int i = 0; i < CR_; ++i) mu += tl[i];
        mu *= (1.f / CR_);
        float var = 0.f;
#pragma unroll
        for (int i = 0; i < CR_; ++i) { const float d = tl[i] - mu; var += d * d; }
        var *= (1.f / CR_);
        tn = (tl[t] - mu) * rsqrtf(var + EPSV) * ln_g[t] + ln_b[t];
        tn = fmaxf(tn, 0.f);
    }
    __syncthreads();
    if (t < CR_) tl[t] = tn;
    __syncthreads();

#pragma unroll
    for (int r = 0; r < 2; ++r) {
        const int c = t + r * 256;
        float g = b2[c];
#pragma unroll
        for (int i = 0; i < CR_; ++i) g += tl[i] * w2[c * CR_ + i];
        g = 1.f / (1.f + expf(-g));
        const float m  = sums[b * C_ + c] * (1.f / HW_);
        const float v  = sqs [b * C_ + c] * (1.f / HW_) - m * m;
        const float rn = rsqrtf(v + EPSV);
        Ab[b * C_ + c] = g + (1.f - g) * rn;
        Db[b * C_ + c] = -(1.f - g) * rn * m;
    }
}

// ---- k5: out = A*x + D (non-temporal stores: out is never re-read, keep L3 for x)
__global__ __launch_bounds__(256) void k5_apply(
    const float* __restrict__ x, const float* __restrict__ Ab, const float* __restrict__ Db,
    float* __restrict__ out, int b0)
{
    const int b = blockIdx.y + b0, c = blockIdx.x, t = threadIdx.x;
    const size_t base = (size_t)(b * C_ + c) * HW_;
    const float a = Ab[b * C_ + c], d = Db[b * C_ + c];
    const float4* px = reinterpret_cast<const float4*>(x + base);
    v4f*          po = reinterpret_cast<v4f*>(out + base);
#pragma unroll
    for (int k = 0; k < 4; ++k) {
        const float4 v = px[t + 256 * k];
        v4f r;
        r.x = fmaf(a, v.x, d); r.y = fmaf(a, v.y, d);
        r.z = fmaf(a, v.z, d); r.w = fmaf(a, v.w, d);
        __builtin_nontemporal_store(r, po + t + 256 * k);
    }
}

extern "C" void kernel_launch(void* const* d_in, const int* in_sizes, int n_in,
                              void* d_out, int out_size, void* d_ws, size_t ws_size,
                              hipStream_t stream)
{
    const float* x      = (const float*)d_in[0];
    const float* w_mask = (const float*)d_in[1];
    // d_in[2] = b_mask: constant shift, cancels in softmax
    const float* w1     = (const float*)d_in[3];
    const float* b1     = (const float*)d_in[4];
    const float* ln_g   = (const float*)d_in[5];
    const float* ln_b   = (const float*)d_in[6];
    const float* w2     = (const float*)d_in[7];
    const float* b2     = (const float*)d_in[8];
    float* out = (float*)d_out;

    float* ws      = (float*)d_ws;
    float* partial = ws;                               // B*NCH*HW = 2M floats (8 MB)
    float* attn    = partial + (size_t)B_ * NCH * HW_; // B*HW
    float* ctx     = attn   + B_ * HW_;                // B*C
    float* sums    = ctx    + B_ * C_;                 // B*C
    float* sqs     = sums   + B_ * C_;                 // B*C
    float* Ab      = sqs    + B_ * C_;                 // B*C
    float* Db      = Ab     + B_ * C_;                 // B*C

    // Chunk over batches so each chunk's x slice (128 MB) stays L3-resident
    // across its three sweeps (k1 read -> k3 read -> k5 read).
    for (int b0 = 0; b0 < B_; b0 += NBC) {
        k1_logits_partial<<<dim3(NCH, NBC, 2), 256, 0, stream>>>(x, w_mask, partial, b0);
        k2_softmax<<<NBC, 256, 0, stream>>>(partial, attn, b0);
        k3_context_stats<<<dim3(C_, NBC), 256, 0, stream>>>(x, attn, ctx, sums, sqs, b0);
        k4_mlp<<<NBC, 256, 0, stream>>>(ctx, w1, b1, ln_g, ln_b, w2, b2, sums, sqs, Ab, Db, b0);
        k5_apply<<<dim3(C_, NBC), 256, 0, stream>>>(x, Ab, Db, out, b0);
    }
}

// Round 7
// 170.348 us; speedup vs baseline: 23.3632x; 1.1532x over previous
//
#include <hip/hip_runtime.h>
#include <math.h>

#define B_   32
#define C_   512
#define CR_  32
#define HW_  4096
#define NCH  16           // channel chunks
#define CPB  (C_/NCH)     // 32 channels per chunk
#define EPSV 1e-5f

typedef float v4f __attribute__((ext_vector_type(4)));

__device__ inline ushort bf16_rne(float f) {
    const unsigned u = __float_as_uint(f);
    return (ushort)((u + 0x7fffu + ((u >> 16) & 1u)) >> 16);
}
__device__ inline float bf16_up(ushort h) {
    return __uint_as_float(((unsigned)h) << 16);
}

// ---- k1: partial logits + bf16 echo of x.
// partial[b][ch][s] = sum_{c in chunk} w[c]*x[b,c,s]; xh = bf16(x).
// x read once (non-temporal), echo written with regular stores (-> L2/L3).
__global__ __launch_bounds__(256) void k1_logits_echo(
    const float* __restrict__ x, const float* __restrict__ w_mask,
    float* __restrict__ partial, ushort* __restrict__ xh)
{
    const int b = blockIdx.y, ch = blockIdx.x, t = threadIdx.x;
    const int s0 = blockIdx.z * 512;            // float4 offset of this half
    const int c0 = ch * CPB;
    v4f a0 = {0,0,0,0}, a1 = {0,0,0,0};
#pragma unroll 4
    for (int cc = 0; cc < CPB; ++cc) {
        const int c = c0 + cc;
        const float w = w_mask[c];
        const v4f* px = reinterpret_cast<const v4f*>(x + (size_t)(b * C_ + c) * HW_) + s0;
        const v4f v0 = __builtin_nontemporal_load(px + t);
        const v4f v1 = __builtin_nontemporal_load(px + t + 256);
        a0 += w * v0;
        a1 += w * v1;
        ushort4* ph = reinterpret_cast<ushort4*>(xh + (size_t)(b * C_ + c) * HW_) + s0;
        ushort4 h0, h1;
        h0.x = bf16_rne(v0.x); h0.y = bf16_rne(v0.y); h0.z = bf16_rne(v0.z); h0.w = bf16_rne(v0.w);
        h1.x = bf16_rne(v1.x); h1.y = bf16_rne(v1.y); h1.z = bf16_rne(v1.z); h1.w = bf16_rne(v1.w);
        ph[t      ] = h0;
        ph[t + 256] = h1;
    }
    v4f* pp = reinterpret_cast<v4f*>(partial + (size_t)(b * NCH + ch) * HW_) + s0;
    pp[t      ] = a0;
    pp[t + 256] = a1;
}

// ---- k2: fused partial-reduce + softmax over HW per batch
__global__ __launch_bounds__(256) void k2_softmax(
    const float* __restrict__ partial, float* __restrict__ attn)
{
    __shared__ float l4[4];
    __shared__ float sM, sZ;
    const int b = blockIdx.x, t = threadIdx.x;
    const int lane = t & 63, wid = t >> 6;
    float4 v[4];
#pragma unroll
    for (int k = 0; k < 4; ++k) {
        float4 s = {0,0,0,0};
        const int i = t + 256 * k;
#pragma unroll
        for (int ch = 0; ch < NCH; ++ch) {
            const float4 p = reinterpret_cast<const float4*>(partial + (size_t)(b * NCH + ch) * HW_)[i];
            s.x += p.x; s.y += p.y; s.z += p.z; s.w += p.w;
        }
        v[k] = s;
    }
    float mx = -3.0e38f;
#pragma unroll
    for (int k = 0; k < 4; ++k)
        mx = fmaxf(mx, fmaxf(fmaxf(v[k].x, v[k].y), fmaxf(v[k].z, v[k].w)));
#pragma unroll
    for (int o = 32; o > 0; o >>= 1) mx = fmaxf(mx, __shfl_down(mx, o));
    if (lane == 0) l4[wid] = mx;
    __syncthreads();
    if (t == 0) sM = fmaxf(fmaxf(l4[0], l4[1]), fmaxf(l4[2], l4[3]));
    __syncthreads();
    const float M = sM;
    float e[16];
    float sum = 0.f;
#pragma unroll
    for (int k = 0; k < 4; ++k) {
        e[k*4+0] = expf(v[k].x - M);
        e[k*4+1] = expf(v[k].y - M);
        e[k*4+2] = expf(v[k].z - M);
        e[k*4+3] = expf(v[k].w - M);
        sum += e[k*4+0] + e[k*4+1] + e[k*4+2] + e[k*4+3];
    }
#pragma unroll
    for (int o = 32; o > 0; o >>= 1) sum += __shfl_down(sum, o);
    __syncthreads();
    if (lane == 0) l4[wid] = sum;
    __syncthreads();
    if (t == 0) sZ = l4[0] + l4[1] + l4[2] + l4[3];
    __syncthreads();
    const float rz = 1.f / sZ;
    float4* pa = reinterpret_cast<float4*>(attn + (size_t)b * HW_);
#pragma unroll
    for (int k = 0; k < 4; ++k)
        pa[t + 256 * k] = make_float4(e[k*4+0]*rz, e[k*4+1]*rz, e[k*4+2]*rz, e[k*4+3]*rz);
}

// ---- k3: context + instance-norm stats from the bf16 echo
__global__ __launch_bounds__(256) void k3_context_stats(
    const ushort* __restrict__ xh, const float* __restrict__ attn,
    float* __restrict__ ctx, float* __restrict__ sums, float* __restrict__ sqs)
{
    __shared__ float ld[12];
    const int b = blockIdx.y, c = blockIdx.x, t = threadIdx.x;
    const int lane = t & 63, wid = t >> 6;
    const ushort4* ph = reinterpret_cast<const ushort4*>(xh + (size_t)(b * C_ + c) * HW_);
    const float4* pa = reinterpret_cast<const float4*>(attn + (size_t)b * HW_);
    float dot = 0.f, sm = 0.f, sq = 0.f;
#pragma unroll
    for (int k = 0; k < 4; ++k) {
        const ushort4 h = ph[t + 256 * k];
        const float4 av = pa[t + 256 * k];
        const float x0 = bf16_up(h.x), x1 = bf16_up(h.y), x2 = bf16_up(h.z), x3 = bf16_up(h.w);
        dot += x0*av.x + x1*av.y + x2*av.z + x3*av.w;
        sm  += x0 + x1 + x2 + x3;
        sq  += x0*x0 + x1*x1 + x2*x2 + x3*x3;
    }
#pragma unroll
    for (int o = 32; o > 0; o >>= 1) {
        dot += __shfl_down(dot, o);
        sm  += __shfl_down(sm, o);
        sq  += __shfl_down(sq, o);
    }
    if (lane == 0) { ld[wid] = dot; ld[4 + wid] = sm; ld[8 + wid] = sq; }
    __syncthreads();
    if (t == 0) {
        ctx [b * C_ + c] = ld[0] + ld[1] + ld[2]  + ld[3];
        sums[b * C_ + c] = ld[4] + ld[5] + ld[6]  + ld[7];
        sqs [b * C_ + c] = ld[8] + ld[9] + ld[10] + ld[11];
    }
}

// ---- k4: MLP gate + fold instance-norm stats into (A,D): out = A*x + D
__global__ __launch_bounds__(256) void k4_mlp(
    const float* __restrict__ ctx, const float* __restrict__ w1, const float* __restrict__ b1,
    const float* __restrict__ ln_g, const float* __restrict__ ln_b,
    const float* __restrict__ w2, const float* __restrict__ b2,
    const float* __restrict__ sums, const float* __restrict__ sqs,
    float* __restrict__ Ab, float* __restrict__ Db)
{
    __shared__ float cs[C_];
    __shared__ float tl[CR_];
    const int b = blockIdx.x, t = threadIdx.x;
    cs[t]       = ctx[b * C_ + t];
    cs[t + 256] = ctx[b * C_ + t + 256];
    __syncthreads();

    const int row = t >> 3, sub = t & 7;
    float p = 0.f;
#pragma unroll 8
    for (int k = 0; k < 64; ++k) {
        const int c = sub + (k << 3);
        p += cs[c] * w1[row * C_ + c];
    }
    p += __shfl_down(p, 4, 8);
    p += __shfl_down(p, 2, 8);
    p += __shfl_down(p, 1, 8);
    if (sub == 0) tl[row] = p + b1[row];
    __syncthreads();

    float tn = 0.f;
    if (t < CR_) {
        float mu = 0.f;
#pragma unroll
        for (int i = 0; i < CR_; ++i) mu += tl[i];
        mu *= (1.f / CR_);
        float var = 0.f;
#pragma unroll
        for (int i = 0; i < CR_; ++i) { const float d = tl[i] - mu; var += d * d; }
        var *= (1.f / CR_);
        tn = (tl[t] - mu) * rsqrtf(var + EPSV) * ln_g[t] + ln_b[t];
        tn = fmaxf(tn, 0.f);
    }
    __syncthreads();
    if (t < CR_) tl[t] = tn;
    __syncthreads();

#pragma unroll
    for (int r = 0; r < 2; ++r) {
        const int c = t + r * 256;
        float g = b2[c];
#pragma unroll
        for (int i = 0; i < CR_; ++i) g += tl[i] * w2[c * CR_ + i];
        g = 1.f / (1.f + expf(-g));
        const float m  = sums[b * C_ + c] * (1.f / HW_);
        const float v  = sqs [b * C_ + c] * (1.f / HW_) - m * m;
        const float rn = rsqrtf(v + EPSV);
        Ab[b * C_ + c] = g + (1.f - g) * rn;
        Db[b * C_ + c] = -(1.f - g) * rn * m;
    }
}

// ---- k5: out = A*xh + D from the echo (non-temporal fp32 stores)
__global__ __launch_bounds__(256) void k5_apply(
    const ushort* __restrict__ xh, const float* __restrict__ Ab, const float* __restrict__ Db,
    float* __restrict__ out)
{
    const int b = blockIdx.y, c = blockIdx.x, t = threadIdx.x;
    const size_t base = (size_t)(b * C_ + c) * HW_;
    const float a = Ab[b * C_ + c], d = Db[b * C_ + c];
    const ushort4* ph = reinterpret_cast<const ushort4*>(xh + base);
    v4f*           po = reinterpret_cast<v4f*>(out + base);
#pragma unroll
    for (int k = 0; k < 4; ++k) {
        const ushort4 h = ph[t + 256 * k];
        v4f r;
        r.x = fmaf(a, bf16_up(h.x), d); r.y = fmaf(a, bf16_up(h.y), d);
        r.z = fmaf(a, bf16_up(h.z), d); r.w = fmaf(a, bf16_up(h.w), d);
        __builtin_nontemporal_store(r, po + t + 256 * k);
    }
}

extern "C" void kernel_launch(void* const* d_in, const int* in_sizes, int n_in,
                              void* d_out, int out_size, void* d_ws, size_t ws_size,
                              hipStream_t stream)
{
    const float* x      = (const float*)d_in[0];
    const float* w_mask = (const float*)d_in[1];
    // d_in[2] = b_mask: constant shift, cancels in softmax
    const float* w1     = (const float*)d_in[3];
    const float* b1     = (const float*)d_in[4];
    const float* ln_g   = (const float*)d_in[5];
    const float* ln_b   = (const float*)d_in[6];
    const float* w2     = (const float*)d_in[7];
    const float* b2     = (const float*)d_in[8];
    float* out = (float*)d_out;

    float* ws      = (float*)d_ws;
    float* partial = ws;                               // B*NCH*HW floats (8 MB)
    float* attn    = partial + (size_t)B_ * NCH * HW_; // B*HW
    float* ctx     = attn   + B_ * HW_;                // B*C
    float* sums    = ctx    + B_ * C_;                 // B*C
    float* sqs     = sums   + B_ * C_;                 // B*C
    float* Ab      = sqs    + B_ * C_;                 // B*C
    float* Db      = Ab     + B_ * C_;                 // B*C
    ushort* xh     = (ushort*)(Db + B_ * C_);          // B*C*HW bf16 echo (128 MB)

    k1_logits_echo<<<dim3(NCH, B_, 2), 256, 0, stream>>>(x, w_mask, partial, xh);
    k2_softmax<<<B_, 256, 0, stream>>>(partial, attn);
    k3_context_stats<<<dim3(C_, B_), 256, 0, stream>>>(xh, attn, ctx, sums, sqs);
    k4_mlp<<<B_, 256, 0, stream>>>(ctx, w1, b1, ln_g, ln_b, w2, b2, sums, sqs, Ab, Db);
    k5_apply<<<dim3(C_, B_), 256, 0, stream>>>(xh, Ab, Db, out);
}